// Round 6
// baseline (3824.662 us; speedup 1.0000x reference)
//
#include <hip/hip_runtime.h>
#include <cstdint>
#include <cstddef>

#define T_STEPS 24
#define BATCH 8
#define CHN 16
#define HH 96
#define WW 96
#define HW (HH*WW)            // 9216
#define NPIX (BATCH*HW)       // 73728
#define NELEM (BATCH*CHN*HW)  // 1179648
#define NBLK 1152             // 64 px per block
#define NGRP 9                // 9 barrier groups x 128 blocks

struct KeyPack { uint32_t k[T_STEPS][2]; };

// Threefry-2x32, 20 rounds — matches jax._src.prng lowering exactly.
__host__ __device__ inline void tf2x32(uint32_t k0, uint32_t k1,
                                       uint32_t x0, uint32_t x1,
                                       uint32_t& o0, uint32_t& o1) {
  const uint32_t ks2 = k0 ^ k1 ^ 0x1BD11BDAu;
  uint32_t v0 = x0 + k0, v1 = x1 + k1;
#define RR(d) { v0 += v1; v1 = (v1 << (d)) | (v1 >> (32 - (d))); v1 ^= v0; }
  RR(13) RR(15) RR(26) RR(6)
  v0 += k1;  v1 += ks2 + 1u;
  RR(17) RR(29) RR(16) RR(24)
  v0 += ks2; v1 += k0 + 2u;
  RR(13) RR(15) RR(26) RR(6)
  v0 += k0;  v1 += k1 + 3u;
  RR(17) RR(29) RR(16) RR(24)
  v0 += k1;  v1 += ks2 + 4u;
  RR(13) RR(15) RR(26) RR(6)
  v0 += ks2; v1 += k0 + 5u;
#undef RR
  o0 = v0; o1 = v1;
}

// One-time: w2 (128h,48k) -> w2t (48k,128h); w3 (16,128) -> w3t (128,16).
// Also zeroes the grid-barrier state (re-zeroed every kernel_launch call).
__global__ __launch_bounds__(256) void wt_transpose(
    const float* __restrict__ w2, const float* __restrict__ w3,
    float* __restrict__ w2t, float* __restrict__ w3t,
    uint32_t* __restrict__ bar)
{
  const int idx = blockIdx.x * 256 + threadIdx.x;   // [0, 8192)
  if (idx < 6144) {
    const int k = idx >> 7, h = idx & 127;
    w2t[idx] = w2[h * 48 + k];
  } else {
    const int i = idx - 6144;                       // [0, 2048)
    const int o = i >> 4, cc = i & 15;
    w3t[i] = w3[cc * 128 + o];
  }
  if (idx < (NGRP + 2) * 32) bar[idx] = 0;          // gcnt[9] | gdone | flag
}

// One NCA step for this block's 64 px. Identical math/order to the verified
// round-5 kernel (register/SGPR-resident GEMMs; mask-on-read). vbid selects
// the pixel region; `mask` false only for t=0.
__device__ __forceinline__ void step_body(
    bool mask, const float* __restrict__ xin, float* __restrict__ frames_prev,
    const uint8_t* __restrict__ alive_prev, float* __restrict__ xnew,
    uint8_t* __restrict__ alive_cur, const float* __restrict__ w2t,
    const float* __restrict__ w3t, uint32_t k0, uint32_t k1,
    float* smem, int vbid)
{
  float* y_t = smem;                               // [48][66]   conv .. GEMM1
  float (*part)[4][64] = (float (*)[4][64])smem;   // [16][4][64] after B2

  const int tid  = threadIdx.x;
  const int lane = tid & 63;
  const int sub  = __builtin_amdgcn_readfirstlane(tid >> 6); // 0..3
  const int P    = vbid * 64;
  const int b    = P / HW;
  const int p0   = P - b * HW;
  const int p    = p0 + lane;
  const int r    = p / WW;
  const int c    = p - r * WW;
  const bool rn = r > 0, rs = r < HH - 1, cw = c > 0, ce = c < WW - 1;

  // ---- Mask-on-read: f at the 9 neighbor positions of p ----
  float f[9];
  #pragma unroll
  for (int i = 0; i < 9; ++i) f[i] = 1.f;
  if (mask) {
    const float* x3 = xin + ((size_t)(b * CHN + 3)) * HW + p;
    const uint8_t* ap = alive_prev + (size_t)b * HW + p;
    const bool rvs[5] = { r > 1, rn, true, rs, r < HH - 2 };
    const bool cvs[5] = { c > 1, cw, true, ce, c < WW - 2 };
    float hm[5][3];                       // horizontal max3, rows r-2..r+2
    #pragma unroll
    for (int i = 0; i < 5; ++i) {
      const int off = (i - 2) * WW;
      const bool rv = rvs[i];
      const float a0 = (rv && cvs[0]) ? x3[off - 2] : 0.f;
      const float a1 = (rv && cvs[1]) ? x3[off - 1] : 0.f;
      const float a2 =  rv            ? x3[off]     : 0.f;
      const float a3 = (rv && cvs[3]) ? x3[off + 1] : 0.f;
      const float a4 = (rv && cvs[4]) ? x3[off + 2] : 0.f;
      hm[i][0] = fmaxf(fmaxf(a0, a1), a2);
      hm[i][1] = fmaxf(fmaxf(a1, a2), a3);
      hm[i][2] = fmaxf(fmaxf(a2, a3), a4);
    }
    #pragma unroll
    for (int qr = 0; qr < 3; ++qr)
      #pragma unroll
      for (int qc = 0; qc < 3; ++qc) {
        const float mp = fmaxf(fmaxf(hm[qr][qc], hm[qr + 1][qc]),
                               hm[qr + 2][qc]);
        const bool inb = rvs[qr + 1] && cvs[qc + 1];
        const uint8_t al = inb ? ap[(qr - 1) * WW + (qc - 1)] : (uint8_t)0;
        f[qr * 3 + qc] = (inb && al && (mp > 0.1f)) ? 1.f : 0.f;
      }
  }

  // ---- Conv on masked values: wave `sub` does channels 4*sub..4*sub+3 ----
  float n11m[4];   // masked center values, reused at writeback
  #pragma unroll
  for (int cq = 0; cq < 4; ++cq) {
    const int ch = sub * 4 + cq;
    const size_t jb = ((size_t)(b * CHN + ch)) * HW + p;
    const float* xc = xin + jb;
    float n00 = (rn && cw) ? xc[-WW - 1] : 0.f;
    float n01 = rn         ? xc[-WW]     : 0.f;
    float n02 = (rn && ce) ? xc[-WW + 1] : 0.f;
    float n10 = cw         ? xc[-1]      : 0.f;
    float n11 =              xc[0];
    float n12 = ce         ? xc[1]       : 0.f;
    float n20 = (rs && cw) ? xc[WW - 1]  : 0.f;
    float n21 = rs         ? xc[WW]      : 0.f;
    float n22 = (rs && ce) ? xc[WW + 1]  : 0.f;
    if (mask) {
      n00 *= f[0]; n01 *= f[1]; n02 *= f[2];
      n10 *= f[3]; n11 *= f[4]; n12 *= f[5];
      n20 *= f[6]; n21 *= f[7]; n22 *= f[8];
      frames_prev[jb] = n11;               // frames[t-1], coalesced 256B/wave
    }
    n11m[cq] = n11;
    y_t[(3 * ch + 0) * 66 + lane] = n11;
    y_t[(3 * ch + 1) * 66 + lane] =
        ((n02 + n22 - n00 - n20) + 2.f * (n12 - n10)) * 0.125f;
    y_t[(3 * ch + 2) * 66 + lane] =
        ((n20 + n22 - n00 - n02) + 2.f * (n21 - n01)) * 0.125f;
    if (ch == 3) {   // wave-uniform branch (only sub==0): alive_pre_t
      float m = fmaxf(fmaxf(fmaxf(n00, n01), fmaxf(n02, n10)),
                      fmaxf(fmaxf(n11, n12), fmaxf(n20, n21)));
      m = fmaxf(m, n22);          // 0-pad == -inf pad for (> 0.1)
      alive_cur[P + lane] = (m > 0.1f) ? 1 : 0;
    }
  }

  // ---- Threefry (pure-register; fills conv-store / barrier latency) ----
  float keep[4];
  #pragma unroll
  for (int i = 0; i < 4; ++i) {
    const int cc = sub * 4 + i;
    const uint32_t j = (uint32_t)((b * CHN + cc) * HW + p);
    uint32_t o0, o1;
    tf2x32(k0, k1, 0u, j, o0, o1);
    const uint32_t bits = o0 ^ o1;
    keep[i] = ((bits >> 9) > 0x400000u) ? 1.f : 0.f;  // uniform>0.5 strict
  }

  __syncthreads();   // B0: y ready

  // ---- GEMM1: lane = px; acc[j] = h[sub*32+j][px]; w2 via s_load ----
  float acc[32];
  #pragma unroll
  for (int j = 0; j < 32; ++j) acc[j] = 0.f;

  const float* w2base = w2t + sub * 32;
  #pragma unroll 2
  for (int k = 0; k < 48; ++k) {
    const float yv = y_t[k * 66 + lane];
    const float* w2r = w2base + k * 128;            // wave-uniform address
    #pragma unroll
    for (int j = 0; j < 32; ++j)
      acc[j] += w2r[j] * yv;
  }

  // ---- GEMM2: relu folds in-register; w3 rows wave-uniform s_load ----
  float o[CHN];
  #pragma unroll
  for (int i = 0; i < CHN; ++i) o[i] = 0.f;

  const float* w3base = w3t + (size_t)sub * 32 * 16;
  #pragma unroll 4
  for (int hh = 0; hh < 32; ++hh) {
    const float hv = fmaxf(acc[hh], 0.f);
    const float* w3r = w3base + hh * 16;            // wave-uniform
    #pragma unroll
    for (int cc = 0; cc < CHN; ++cc)
      o[cc] += w3r[cc] * hv;
  }

  __syncthreads();   // B2: all y reads done; region becomes part[][][]

  #pragma unroll
  for (int cc = 0; cc < CHN; ++cc)
    part[cc][sub][lane] = o[cc];
  __syncthreads();   // B3

  // ---- Writeback: 4 (px,channel) per thread, coalesced ----
  #pragma unroll
  for (int i = 0; i < 4; ++i) {
    const int cc = sub * 4 + i;
    const float s = (part[cc][0][lane] + part[cc][1][lane]) +
                    (part[cc][2][lane] + part[cc][3][lane]);
    const uint32_t j = (uint32_t)((b * CHN + cc) * HW + p);
    xnew[j] = n11m[i] + keep[i] * s;
  }
}

// Persistent cooperative kernel: all 24 steps + final mask in ONE dispatch.
// Grid barrier: two-level (9 groups x 128), monotonic phases, device-scope
// fences (G16). XCD swizzle: vbid = (bid%8)*144 + bid/8 -> image b lives
// entirely on XCD b (1152 = 8 images x 144 blocks): halos XCD-local.
__global__ __launch_bounds__(256, 5) void nca_persistent(
    const float* __restrict__ x0, float* __restrict__ out,
    float* __restrict__ xlast, uint8_t* __restrict__ aliveA,
    uint8_t* __restrict__ aliveB, const float* __restrict__ w2t,
    const float* __restrict__ w3t, uint32_t* __restrict__ bar, KeyPack keys)
{
  __shared__ float smem[4096];                     // 16384 B
  const int bid  = blockIdx.x;
  const int vbid = (bid & 7) * 144 + (bid >> 3);   // bijection on [0,1152)
  uint32_t* gcnt  = bar + (size_t)(bid >> 7) * 32; // 9 groups, 128B-padded
  uint32_t* gdone = bar + NGRP * 32;
  uint32_t* flag  = bar + (NGRP + 1) * 32;

  for (int t = 0; t < T_STEPS; ++t) {
    const float* xin  = (t == 0) ? x0 : out + (size_t)t * NELEM;
    float* fprev = (t == 0) ? nullptr : out + (size_t)(t - 1) * NELEM;
    float* xdst  = (t < T_STEPS - 1) ? out + (size_t)(t + 1) * NELEM : xlast;
    const uint8_t* ar = (t & 1) ? aliveA : aliveB;
    uint8_t*       aw = (t & 1) ? aliveB : aliveA;
    step_body(t != 0, xin, fprev, ar, xdst, aw, w2t, w3t,
              keys.k[t][0], keys.k[t][1], smem, vbid);

    // ---- grid barrier, phase t+1 (monotonic counters; no reset race) ----
    __syncthreads();
    if (threadIdx.x == 0) {
      __threadfence();                              // release block's stores
      const uint32_t ph = (uint32_t)(t + 1);
      uint32_t old = atomicAdd((unsigned int*)gcnt, 1u);
      if (old == ph * 128u - 1u) {                  // last in group
        uint32_t od = atomicAdd((unsigned int*)gdone, 1u);
        if (od == ph * (uint32_t)NGRP - 1u) {       // last group
          __threadfence();
          atomicExch((unsigned int*)flag, ph);
        }
      }
      while (__hip_atomic_load(flag, __ATOMIC_ACQUIRE,
                               __HIP_MEMORY_SCOPE_AGENT) < ph) {
        __builtin_amdgcn_s_sleep(2);
      }
      __threadfence();                              // acquire others' stores
    }
    __syncthreads();
  }

  // ---- Final mask: frames[23] = f_23 * xlast (3x3 maxpool of xlast ch3) ----
  {
    const int lane = threadIdx.x & 63;
    const int sub  = threadIdx.x >> 6;
    const int P    = vbid * 64;
    const int b    = P / HW;
    const int p    = P - b * HW + lane;
    const int r    = p / WW;
    const int c    = p - r * WW;
    const bool rn = r > 0, rs = r < HH - 1, cw = c > 0, ce = c < WW - 1;
    const float* x3 = xlast + ((size_t)b * CHN + 3) * HW + p;
    float m = x3[0];
    if (rn) {
      m = fmaxf(m, x3[-WW]);
      if (cw) m = fmaxf(m, x3[-WW - 1]);
      if (ce) m = fmaxf(m, x3[-WW + 1]);
    }
    if (cw) m = fmaxf(m, x3[-1]);
    if (ce) m = fmaxf(m, x3[1]);
    if (rs) {
      m = fmaxf(m, x3[WW]);
      if (cw) m = fmaxf(m, x3[WW - 1]);
      if (ce) m = fmaxf(m, x3[WW + 1]);
    }
    const float ff = ((m > 0.1f) && aliveB[P + lane]) ? 1.f : 0.f;  // t=23 odd
    float* out23 = out + (size_t)(T_STEPS - 1) * NELEM;
    #pragma unroll
    for (int i = 0; i < 4; ++i) {
      const int cc = sub * 4 + i;
      const uint32_t j = (uint32_t)((b * CHN + cc) * HW + p);
      out23[j] = xlast[j] * ff;
    }
  }
}

// ---- Fallback path (round-5 verified): per-step dispatches ----
template <bool MASK>
__global__ __launch_bounds__(256, 5) void nca_step(
    const float* __restrict__ xin, float* __restrict__ frames_prev,
    const uint8_t* __restrict__ alive_prev, float* __restrict__ xnew,
    uint8_t* __restrict__ alive_cur, const float* __restrict__ w2t,
    const float* __restrict__ w3t, uint32_t k0, uint32_t k1)
{
  __shared__ float smem[4096];
  step_body(MASK, xin, frames_prev, alive_prev, xnew, alive_cur,
            w2t, w3t, k0, k1, smem, blockIdx.x);
}

__global__ __launch_bounds__(256) void nca_mask(
    const float* __restrict__ xnew, const uint8_t* __restrict__ alive_pre,
    float* __restrict__ xout)
{
  const int lane = threadIdx.x & 63;
  const int quad = threadIdx.x >> 6;
  const int pix  = blockIdx.x * 64 + lane;
  const int b = pix / HW;
  const int p = pix - b * HW;
  const int r = p / WW;
  const int c = p - r * WW;
  const bool rn = r > 0, rs = r < HH - 1, cw = c > 0, ce = c < WW - 1;

  const float* x3 = xnew + ((size_t)b * CHN + 3) * HW + p;
  float m = x3[0];
  if (rn) {
    m = fmaxf(m, x3[-WW]);
    if (cw) m = fmaxf(m, x3[-WW - 1]);
    if (ce) m = fmaxf(m, x3[-WW + 1]);
  }
  if (cw) m = fmaxf(m, x3[-1]);
  if (ce) m = fmaxf(m, x3[1]);
  if (rs) {
    m = fmaxf(m, x3[WW]);
    if (cw) m = fmaxf(m, x3[WW - 1]);
    if (ce) m = fmaxf(m, x3[WW + 1]);
  }
  const float f = ((m > 0.1f) && alive_pre[pix]) ? 1.f : 0.f;

  const size_t base = ((size_t)b * CHN + quad * 4) * HW + p;
  #pragma unroll
  for (int i = 0; i < 4; ++i)
    xout[base + (size_t)i * HW] = xnew[base + (size_t)i * HW] * f;
}

extern "C" void kernel_launch(void* const* d_in, const int* in_sizes, int n_in,
                              void* d_out, int out_size, void* d_ws, size_t ws_size,
                              hipStream_t stream) {
  const float* x0 = (const float*)d_in[0];
  // d_in[1] = num_steps (24, fixed), d_in[2] = dw_kernel (fixed, hardcoded)
  const float* w2 = (const float*)d_in[3];  // (128,48)
  const float* w3 = (const float*)d_in[4];  // (16,128)
  float* out = (float*)d_out;               // (24,8,16,96,96)

  // ws: xlast | aliveA | aliveB | w3t | w2t | barrier  (~4.76 MB)
  char* ws = (char*)d_ws;
  float*    xlast  = (float*)ws;                                 // NELEM f32
  uint8_t*  aliveA = (uint8_t*)(ws + (size_t)NELEM * 4);         // NPIX B
  uint8_t*  aliveB = aliveA + NPIX;                              // NPIX B
  float*    w3t    = (float*)(ws + (size_t)NELEM * 4 + 2 * (size_t)NPIX);
  float*    w2t    = w3t + 2048;                                 // 6144 f32
  uint32_t* bar    = (uint32_t*)(w2t + 6144);                    // 11*32 u32

  // Step keys: partitionable split => key_t = tf((0,42),(0,t)) full pair.
  KeyPack kp;
  for (int t = 0; t < T_STEPS; ++t) {
    uint32_t a, b;
    tf2x32(0u, 42u, 0u, (uint32_t)t, a, b);
    kp.k[t][0] = a; kp.k[t][1] = b;
  }

  wt_transpose<<<32, 256, 0, stream>>>(w2, w3, w2t, w3t, bar);

  // Cooperative persistent launch (1152 blocks <= 5/CU * 256 CU).
  const float* x0p = x0;  float* outp = out;  float* xlp = xlast;
  uint8_t* aAp = aliveA;  uint8_t* aBp = aliveB;
  const float* w2tp = w2t;  const float* w3tp = w3t;  uint32_t* barp = bar;
  void* args[] = { &x0p, &outp, &xlp, &aAp, &aBp, &w2tp, &w3tp, &barp, &kp };
  hipError_t e = hipLaunchCooperativeKernel(
      (const void*)nca_persistent, dim3(NBLK), dim3(256), args, 0, stream);

  if (e != hipSuccess) {
    // Fallback: round-5 verified per-step dispatch loop.
    nca_step<false><<<NBLK, 256, 0, stream>>>(
        x0, nullptr, nullptr, out + (size_t)1 * NELEM, aliveA, w2t, w3t,
        kp.k[0][0], kp.k[0][1]);
    for (int t = 1; t < T_STEPS; ++t) {
      const float* xin  = out + (size_t)t * NELEM;
      float* frames_prv = out + (size_t)(t - 1) * NELEM;
      float* xdst = (t < T_STEPS - 1) ? out + (size_t)(t + 1) * NELEM : xlast;
      const uint8_t* aprev = (t & 1) ? aliveA : aliveB;
      uint8_t*       acur  = (t & 1) ? aliveB : aliveA;
      nca_step<true><<<NBLK, 256, 0, stream>>>(
          xin, frames_prv, aprev, xdst, acur, w2t, w3t,
          kp.k[t][0], kp.k[t][1]);
    }
    nca_mask<<<NBLK, 256, 0, stream>>>(
        xlast, aliveB, out + (size_t)(T_STEPS - 1) * NELEM);
  }
}

// Round 8
// 689.760 us; speedup vs baseline: 5.5449x; 5.5449x over previous
//
#include <hip/hip_runtime.h>
#include <cstdint>
#include <cstddef>

#define T_STEPS 24
#define BATCH 8
#define CHN 16
#define HH 96
#define WW 96
#define HW (HH*WW)            // 9216
#define NPIX (BATCH*HW)       // 73728
#define NELEM (BATCH*CHN*HW)  // 1179648
#define NBLK 1152             // 64 px per block

typedef float f32x2 __attribute__((ext_vector_type(2)));

// Threefry-2x32, 20 rounds — matches jax._src.prng lowering exactly.
__host__ __device__ inline void tf2x32(uint32_t k0, uint32_t k1,
                                       uint32_t x0, uint32_t x1,
                                       uint32_t& o0, uint32_t& o1) {
  const uint32_t ks2 = k0 ^ k1 ^ 0x1BD11BDAu;
  uint32_t v0 = x0 + k0, v1 = x1 + k1;
#define RR(d) { v0 += v1; v1 = (v1 << (d)) | (v1 >> (32 - (d))); v1 ^= v0; }
  RR(13) RR(15) RR(26) RR(6)
  v0 += k1;  v1 += ks2 + 1u;
  RR(17) RR(29) RR(16) RR(24)
  v0 += ks2; v1 += k0 + 2u;
  RR(13) RR(15) RR(26) RR(6)
  v0 += k0;  v1 += k1 + 3u;
  RR(17) RR(29) RR(16) RR(24)
  v0 += k1;  v1 += ks2 + 4u;
  RR(13) RR(15) RR(26) RR(6)
  v0 += ks2; v1 += k0 + 5u;
#undef RR
  o0 = v0; o1 = v1;
}

// One-time: w2 (128h,48k) -> w2t (48k,128h); w3 (16,128) -> w3t (128,16).
__global__ __launch_bounds__(256) void wt_transpose(
    const float* __restrict__ w2, const float* __restrict__ w3,
    float* __restrict__ w2t, float* __restrict__ w3t)
{
  const int idx = blockIdx.x * 256 + threadIdx.x;   // [0, 8192)
  if (idx < 6144) {
    const int k = idx >> 7, h = idx & 127;
    w2t[idx] = w2[h * 48 + k];
  } else {
    const int i = idx - 6144;                       // [0, 2048)
    const int o = i >> 4, cc = i & 15;
    w3t[i] = w3[cc * 128 + o];
  }
}

// Fused step kernel, register/SGPR-resident GEMMs.
//   GEMM1/GEMM2 FULLY unrolled (all register-array indices compile-time —
//   rule #20: partial unroll put acc[] in scratch, VGPR_Count=32 proved it)
//   and written on f32x2 with __builtin_elementwise_fma -> v_pk_fma_f32
//   (halves VALU issue; per-output k-ascending chain order unchanged, exact).
template <bool MASK>
__global__ __launch_bounds__(256, 5) void nca_step(
    const float* __restrict__ xin,         // raw xnew_{t-1} (or x0 when !MASK)
    float* __restrict__ frames_prev,       // out[t-1]           (MASK only)
    const uint8_t* __restrict__ alive_prev,//                    (MASK only)
    float* __restrict__ xnew,              // raw xnew_t destination
    uint8_t* __restrict__ alive_cur,       // alive_pre_t
    const float* __restrict__ w2t, const float* __restrict__ w3t,
    uint32_t k0, uint32_t k1)
{
  __shared__ float smem[4096];                     // 16384 B
  float* y_t = smem;                               // [48][66]   conv .. GEMM1
  float (*part)[4][64] = (float (*)[4][64])smem;   // [16][4][64] after B2

  const int tid  = threadIdx.x;
  const int lane = tid & 63;
  const int sub  = __builtin_amdgcn_readfirstlane(tid >> 6); // 0..3
  const int P    = blockIdx.x * 64;
  const int b    = P / HW;
  const int p0   = P - b * HW;
  const int p    = p0 + lane;
  const int r    = p / WW;
  const int c    = p - r * WW;
  const bool rn = r > 0, rs = r < HH - 1, cw = c > 0, ce = c < WW - 1;

  // ---- Mask-on-read: f at the 9 neighbor positions of p ----
  // f(q) = alive_prev(q) & (maxpool3(xin ch3)(q) > 0.1). Needs ch3 over
  // 5x5(p). 0-substitution for OOB is exact vs -inf pad (0 < 0.1).
  float f[9];
  #pragma unroll
  for (int i = 0; i < 9; ++i) f[i] = 1.f;
  if constexpr (MASK) {
    const float* x3 = xin + ((size_t)(b * CHN + 3)) * HW + p;
    const uint8_t* ap = alive_prev + (size_t)b * HW + p;
    const bool rvs[5] = { r > 1, rn, true, rs, r < HH - 2 };
    const bool cvs[5] = { c > 1, cw, true, ce, c < WW - 2 };
    float hm[5][3];                       // horizontal max3, rows r-2..r+2
    #pragma unroll
    for (int i = 0; i < 5; ++i) {
      const int off = (i - 2) * WW;
      const bool rv = rvs[i];
      const float a0 = (rv && cvs[0]) ? x3[off - 2] : 0.f;
      const float a1 = (rv && cvs[1]) ? x3[off - 1] : 0.f;
      const float a2 =  rv            ? x3[off]     : 0.f;
      const float a3 = (rv && cvs[3]) ? x3[off + 1] : 0.f;
      const float a4 = (rv && cvs[4]) ? x3[off + 2] : 0.f;
      hm[i][0] = fmaxf(fmaxf(a0, a1), a2);
      hm[i][1] = fmaxf(fmaxf(a1, a2), a3);
      hm[i][2] = fmaxf(fmaxf(a2, a3), a4);
    }
    #pragma unroll
    for (int qr = 0; qr < 3; ++qr)
      #pragma unroll
      for (int qc = 0; qc < 3; ++qc) {
        const float mp = fmaxf(fmaxf(hm[qr][qc], hm[qr + 1][qc]),
                               hm[qr + 2][qc]);
        const bool inb = rvs[qr + 1] && cvs[qc + 1];
        const uint8_t al = inb ? ap[(qr - 1) * WW + (qc - 1)] : (uint8_t)0;
        f[qr * 3 + qc] = (inb && al && (mp > 0.1f)) ? 1.f : 0.f;
      }
  }

  // ---- Conv on masked values: wave `sub` does channels 4*sub..4*sub+3 ----
  float n11m[4];   // masked center values, reused at writeback
  #pragma unroll
  for (int cq = 0; cq < 4; ++cq) {
    const int ch = sub * 4 + cq;
    const size_t jb = ((size_t)(b * CHN + ch)) * HW + p;
    const float* xc = xin + jb;
    float n00 = (rn && cw) ? xc[-WW - 1] : 0.f;
    float n01 = rn         ? xc[-WW]     : 0.f;
    float n02 = (rn && ce) ? xc[-WW + 1] : 0.f;
    float n10 = cw         ? xc[-1]      : 0.f;
    float n11 =              xc[0];
    float n12 = ce         ? xc[1]       : 0.f;
    float n20 = (rs && cw) ? xc[WW - 1]  : 0.f;
    float n21 = rs         ? xc[WW]      : 0.f;
    float n22 = (rs && ce) ? xc[WW + 1]  : 0.f;
    if constexpr (MASK) {
      n00 *= f[0]; n01 *= f[1]; n02 *= f[2];
      n10 *= f[3]; n11 *= f[4]; n12 *= f[5];
      n20 *= f[6]; n21 *= f[7]; n22 *= f[8];
      frames_prev[jb] = n11;               // frames[t-1], coalesced 256B/wave
    }
    n11m[cq] = n11;
    y_t[(3 * ch + 0) * 66 + lane] = n11;
    y_t[(3 * ch + 1) * 66 + lane] =
        ((n02 + n22 - n00 - n20) + 2.f * (n12 - n10)) * 0.125f;
    y_t[(3 * ch + 2) * 66 + lane] =
        ((n20 + n22 - n00 - n02) + 2.f * (n21 - n01)) * 0.125f;
    if (ch == 3) {   // wave-uniform branch (only sub==0): alive_pre_t
      float m = fmaxf(fmaxf(fmaxf(n00, n01), fmaxf(n02, n10)),
                      fmaxf(fmaxf(n11, n12), fmaxf(n20, n21)));
      m = fmaxf(m, n22);          // 0-pad == -inf pad for (> 0.1)
      alive_cur[P + lane] = (m > 0.1f) ? 1 : 0;
    }
  }

  // ---- Threefry (pure-register; fills conv-store / barrier latency) ----
  float keep[4];
  #pragma unroll
  for (int i = 0; i < 4; ++i) {
    const int cc = sub * 4 + i;
    const uint32_t j = (uint32_t)((b * CHN + cc) * HW + p);
    uint32_t o0, o1;
    tf2x32(k0, k1, 0u, j, o0, o1);
    const uint32_t bits = o0 ^ o1;
    keep[i] = ((bits >> 9) > 0x400000u) ? 1.f : 0.f;  // uniform>0.5 strict
  }

  __syncthreads();   // B0: y ready

  // ---- GEMM1: lane = px; acc[j] = h pair {sub*32+2j, sub*32+2j+1}[px].
  //      FULL unroll; w2 pairs wave-uniform (SGPR) -> v_pk_fma_f32. ----
  f32x2 acc[16];
  #pragma unroll
  for (int j = 0; j < 16; ++j) acc[j] = (f32x2){0.f, 0.f};

  const f32x2* w2b2 = (const f32x2*)(w2t + sub * 32);
  #pragma unroll
  for (int k = 0; k < 48; ++k) {
    const float yv = y_t[k * 66 + lane];
    const f32x2 yv2 = {yv, yv};
    const f32x2* w2r = w2b2 + k * 64;               // wave-uniform address
    #pragma unroll
    for (int j = 0; j < 16; ++j)
      acc[j] = __builtin_elementwise_fma(w2r[j], yv2, acc[j]);
  }

  // ---- GEMM2: relu in-register; FULL unroll (compile-time acc index);
  //      w3 pairs wave-uniform -> v_pk_fma_f32. hh ascending (same order). ----
  f32x2 o2[8];
  #pragma unroll
  for (int i = 0; i < 8; ++i) o2[i] = (f32x2){0.f, 0.f};

  const f32x2* w3b2 = (const f32x2*)(w3t + (size_t)sub * 32 * 16);
  #pragma unroll
  for (int hh = 0; hh < 32; ++hh) {
    const float av = (hh & 1) ? acc[hh >> 1].y : acc[hh >> 1].x;
    const float hv = fmaxf(av, 0.f);
    const f32x2 hv2 = {hv, hv};
    const f32x2* w3r = w3b2 + hh * 8;               // wave-uniform
    #pragma unroll
    for (int n = 0; n < 8; ++n)
      o2[n] = __builtin_elementwise_fma(w3r[n], hv2, o2[n]);
  }

  __syncthreads();   // B2: all y reads done; region becomes part[][][]

  #pragma unroll
  for (int cc = 0; cc < CHN; ++cc)
    part[cc][sub][lane] = (cc & 1) ? o2[cc >> 1].y : o2[cc >> 1].x;
  __syncthreads();   // B3

  // ---- Writeback: 4 (px,channel) per thread, coalesced; base value from
  //      the conv's (masked) center registers — no xin re-read. ----
  #pragma unroll
  for (int i = 0; i < 4; ++i) {
    const int cc = sub * 4 + i;
    const float s = (part[cc][0][lane] + part[cc][1][lane]) +
                    (part[cc][2][lane] + part[cc][3][lane]);
    const uint32_t j = (uint32_t)((b * CHN + cc) * HW + p);
    xnew[j] = n11m[i] + keep[i] * s;
  }
}

// Final mask pass (only for frames[23]): thread per (pixel, channel-quad).
__global__ __launch_bounds__(256) void nca_mask(
    const float* __restrict__ xnew, const uint8_t* __restrict__ alive_pre,
    float* __restrict__ xout)
{
  const int lane = threadIdx.x & 63;
  const int quad = threadIdx.x >> 6;            // 0..3
  const int pix  = blockIdx.x * 64 + lane;      // [0, NPIX)
  const int b = pix / HW;
  const int p = pix - b * HW;
  const int r = p / WW;
  const int c = p - r * WW;
  const bool rn = r > 0, rs = r < HH - 1, cw = c > 0, ce = c < WW - 1;

  const float* x3 = xnew + ((size_t)b * CHN + 3) * HW + p;
  float m = x3[0];
  if (rn) {
    m = fmaxf(m, x3[-WW]);
    if (cw) m = fmaxf(m, x3[-WW - 1]);
    if (ce) m = fmaxf(m, x3[-WW + 1]);
  }
  if (cw) m = fmaxf(m, x3[-1]);
  if (ce) m = fmaxf(m, x3[1]);
  if (rs) {
    m = fmaxf(m, x3[WW]);
    if (cw) m = fmaxf(m, x3[WW - 1]);
    if (ce) m = fmaxf(m, x3[WW + 1]);
  }
  const float f = ((m > 0.1f) && alive_pre[pix]) ? 1.f : 0.f;

  const size_t base = ((size_t)b * CHN + quad * 4) * HW + p;
  #pragma unroll
  for (int i = 0; i < 4; ++i)
    xout[base + (size_t)i * HW] = xnew[base + (size_t)i * HW] * f;
}

extern "C" void kernel_launch(void* const* d_in, const int* in_sizes, int n_in,
                              void* d_out, int out_size, void* d_ws, size_t ws_size,
                              hipStream_t stream) {
  const float* x0 = (const float*)d_in[0];
  // d_in[1] = num_steps (24, fixed), d_in[2] = dw_kernel (fixed, hardcoded)
  const float* w2 = (const float*)d_in[3];  // (128,48)
  const float* w3 = (const float*)d_in[4];  // (16,128)
  float* out = (float*)d_out;               // (24,8,16,96,96)

  // ws layout: xlast (xnew_23) | aliveA | aliveB | w3t | w2t  (~4.9 MB)
  char* ws = (char*)d_ws;
  float*   xlast  = (float*)ws;                                  // NELEM f32
  uint8_t* aliveA = (uint8_t*)(ws + (size_t)NELEM * 4);          // NPIX B
  uint8_t* aliveB = aliveA + NPIX;                               // NPIX B
  float*   w3t    = (float*)(ws + (size_t)NELEM * 4 + 2 * (size_t)NPIX);
  float*   w2t    = w3t + 2048;                                  // 6144 f32

  // Step keys: partitionable split => key_t = tf((0,42),(0,t)) full pair.
  uint32_t keys[T_STEPS][2];
  for (int t = 0; t < T_STEPS; ++t) {
    uint32_t a, b;
    tf2x32(0u, 42u, 0u, (uint32_t)t, a, b);
    keys[t][0] = a; keys[t][1] = b;
  }

  wt_transpose<<<32, 256, 0, stream>>>(w2, w3, w2t, w3t);

  // Buffer schedule: raw xnew_t parked in out[t+1] (free until frames[t+1]
  // lands there two dispatches later); xnew_23 goes to ws.
  //   F_0:  x0      -> out[1]
  //   F_t:  out[t]  -> frames[t-1]=out[t-1], xnew_t -> out[t+1] (t=1..22)
  //   F_23: out[23] -> frames[22]=out[22],  xnew_23 -> ws
  //   final mask: ws -> frames[23]=out[23]
  nca_step<false><<<NBLK, 256, 0, stream>>>(
      x0, nullptr, nullptr, out + (size_t)1 * NELEM, aliveA, w2t, w3t,
      keys[0][0], keys[0][1]);

  for (int t = 1; t < T_STEPS; ++t) {
    const float* xin  = out + (size_t)t * NELEM;          // raw xnew_{t-1}
    float* frames_prv = out + (size_t)(t - 1) * NELEM;
    float* xdst = (t < T_STEPS - 1) ? out + (size_t)(t + 1) * NELEM : xlast;
    const uint8_t* aprev = (t & 1) ? aliveA : aliveB;
    uint8_t*       acur  = (t & 1) ? aliveB : aliveA;
    nca_step<true><<<NBLK, 256, 0, stream>>>(
        xin, frames_prv, aprev, xdst, acur, w2t, w3t,
        keys[t][0], keys[t][1]);
  }

  nca_mask<<<NBLK, 256, 0, stream>>>(
      xlast, (T_STEPS & 1) ? aliveA : aliveB,
      out + (size_t)(T_STEPS - 1) * NELEM);
}

// Round 9
// 661.852 us; speedup vs baseline: 5.7787x; 1.0422x over previous
//
#include <hip/hip_runtime.h>
#include <cstdint>
#include <cstddef>

#define T_STEPS 24
#define BATCH 8
#define CHN 16
#define HH 96
#define WW 96
#define HW (HH*WW)            // 9216
#define NPIX (BATCH*HW)       // 73728
#define NELEM (BATCH*CHN*HW)  // 1179648
#define NBLK 1152             // 64 px per block

typedef float f32x2 __attribute__((ext_vector_type(2)));

// Threefry-2x32, 20 rounds — matches jax._src.prng lowering exactly.
__host__ __device__ inline void tf2x32(uint32_t k0, uint32_t k1,
                                       uint32_t x0, uint32_t x1,
                                       uint32_t& o0, uint32_t& o1) {
  const uint32_t ks2 = k0 ^ k1 ^ 0x1BD11BDAu;
  uint32_t v0 = x0 + k0, v1 = x1 + k1;
#define RR(d) { v0 += v1; v1 = (v1 << (d)) | (v1 >> (32 - (d))); v1 ^= v0; }
  RR(13) RR(15) RR(26) RR(6)
  v0 += k1;  v1 += ks2 + 1u;
  RR(17) RR(29) RR(16) RR(24)
  v0 += ks2; v1 += k0 + 2u;
  RR(13) RR(15) RR(26) RR(6)
  v0 += k0;  v1 += k1 + 3u;
  RR(17) RR(29) RR(16) RR(24)
  v0 += k1;  v1 += ks2 + 4u;
  RR(13) RR(15) RR(26) RR(6)
  v0 += ks2; v1 += k0 + 5u;
#undef RR
  o0 = v0; o1 = v1;
}

// One-time: w2 (128h,48k) -> w2t (48k,128h); w3 (16,128) -> w3t (128,16).
__global__ __launch_bounds__(256) void wt_transpose(
    const float* __restrict__ w2, const float* __restrict__ w3,
    float* __restrict__ w2t, float* __restrict__ w3t)
{
  const int idx = blockIdx.x * 256 + threadIdx.x;   // [0, 8192)
  if (idx < 6144) {
    const int k = idx >> 7, h = idx & 127;
    w2t[idx] = w2[h * 48 + k];
  } else {
    const int i = idx - 6144;                       // [0, 2048)
    const int o = i >> 4, cc = i & 15;
    w3t[i] = w3[cc * 128 + o];
  }
}

// Fused step kernel, register/SGPR-resident GEMMs (round-8 verified body).
// XCD swizzle (T1, cross-dispatch variant): vbid = (bid&7)*144 + bid>>3.
// 1152 = 8 images x 144 blocks and HW/64 = 144, so image b lives entirely
// on XCD b (assuming bid%8 round-robin XCD assignment): all halo reads and
// all step-to-step state reuse are XCD-local L2 hits instead of LLC/cross-
// die. Pure block->px permutation — per-px math unchanged.
template <bool MASK>
__global__ __launch_bounds__(256, 5) void nca_step(
    const float* __restrict__ xin,         // raw xnew_{t-1} (or x0 when !MASK)
    float* __restrict__ frames_prev,       // out[t-1]           (MASK only)
    const uint8_t* __restrict__ alive_prev,//                    (MASK only)
    float* __restrict__ xnew,              // raw xnew_t destination
    uint8_t* __restrict__ alive_cur,       // alive_pre_t
    const float* __restrict__ w2t, const float* __restrict__ w3t,
    uint32_t k0, uint32_t k1)
{
  __shared__ float smem[4096];                     // 16384 B
  float* y_t = smem;                               // [48][66]   conv .. GEMM1
  float (*part)[4][64] = (float (*)[4][64])smem;   // [16][4][64] after B2

  const int tid  = threadIdx.x;
  const int lane = tid & 63;
  const int sub  = __builtin_amdgcn_readfirstlane(tid >> 6); // 0..3
  const int bid  = blockIdx.x;
  const int vbid = (bid & 7) * 144 + (bid >> 3);   // XCD-bijective swizzle
  const int P    = vbid * 64;
  const int b    = P / HW;
  const int p0   = P - b * HW;
  const int p    = p0 + lane;
  const int r    = p / WW;
  const int c    = p - r * WW;
  const bool rn = r > 0, rs = r < HH - 1, cw = c > 0, ce = c < WW - 1;

  // ---- Mask-on-read: f at the 9 neighbor positions of p ----
  // f(q) = alive_prev(q) & (maxpool3(xin ch3)(q) > 0.1). Needs ch3 over
  // 5x5(p). 0-substitution for OOB is exact vs -inf pad (0 < 0.1).
  float f[9];
  #pragma unroll
  for (int i = 0; i < 9; ++i) f[i] = 1.f;
  if constexpr (MASK) {
    const float* x3 = xin + ((size_t)(b * CHN + 3)) * HW + p;
    const uint8_t* ap = alive_prev + (size_t)b * HW + p;
    const bool rvs[5] = { r > 1, rn, true, rs, r < HH - 2 };
    const bool cvs[5] = { c > 1, cw, true, ce, c < WW - 2 };
    float hm[5][3];                       // horizontal max3, rows r-2..r+2
    #pragma unroll
    for (int i = 0; i < 5; ++i) {
      const int off = (i - 2) * WW;
      const bool rv = rvs[i];
      const float a0 = (rv && cvs[0]) ? x3[off - 2] : 0.f;
      const float a1 = (rv && cvs[1]) ? x3[off - 1] : 0.f;
      const float a2 =  rv            ? x3[off]     : 0.f;
      const float a3 = (rv && cvs[3]) ? x3[off + 1] : 0.f;
      const float a4 = (rv && cvs[4]) ? x3[off + 2] : 0.f;
      hm[i][0] = fmaxf(fmaxf(a0, a1), a2);
      hm[i][1] = fmaxf(fmaxf(a1, a2), a3);
      hm[i][2] = fmaxf(fmaxf(a2, a3), a4);
    }
    #pragma unroll
    for (int qr = 0; qr < 3; ++qr)
      #pragma unroll
      for (int qc = 0; qc < 3; ++qc) {
        const float mp = fmaxf(fmaxf(hm[qr][qc], hm[qr + 1][qc]),
                               hm[qr + 2][qc]);
        const bool inb = rvs[qr + 1] && cvs[qc + 1];
        const uint8_t al = inb ? ap[(qr - 1) * WW + (qc - 1)] : (uint8_t)0;
        f[qr * 3 + qc] = (inb && al && (mp > 0.1f)) ? 1.f : 0.f;
      }
  }

  // ---- Conv on masked values: wave `sub` does channels 4*sub..4*sub+3 ----
  float n11m[4];   // masked center values, reused at writeback
  #pragma unroll
  for (int cq = 0; cq < 4; ++cq) {
    const int ch = sub * 4 + cq;
    const size_t jb = ((size_t)(b * CHN + ch)) * HW + p;
    const float* xc = xin + jb;
    float n00 = (rn && cw) ? xc[-WW - 1] : 0.f;
    float n01 = rn         ? xc[-WW]     : 0.f;
    float n02 = (rn && ce) ? xc[-WW + 1] : 0.f;
    float n10 = cw         ? xc[-1]      : 0.f;
    float n11 =              xc[0];
    float n12 = ce         ? xc[1]       : 0.f;
    float n20 = (rs && cw) ? xc[WW - 1]  : 0.f;
    float n21 = rs         ? xc[WW]      : 0.f;
    float n22 = (rs && ce) ? xc[WW + 1]  : 0.f;
    if constexpr (MASK) {
      n00 *= f[0]; n01 *= f[1]; n02 *= f[2];
      n10 *= f[3]; n11 *= f[4]; n12 *= f[5];
      n20 *= f[6]; n21 *= f[7]; n22 *= f[8];
      frames_prev[jb] = n11;               // frames[t-1], coalesced 256B/wave
    }
    n11m[cq] = n11;
    y_t[(3 * ch + 0) * 66 + lane] = n11;
    y_t[(3 * ch + 1) * 66 + lane] =
        ((n02 + n22 - n00 - n20) + 2.f * (n12 - n10)) * 0.125f;
    y_t[(3 * ch + 2) * 66 + lane] =
        ((n20 + n22 - n00 - n02) + 2.f * (n21 - n01)) * 0.125f;
    if (ch == 3) {   // wave-uniform branch (only sub==0): alive_pre_t
      float m = fmaxf(fmaxf(fmaxf(n00, n01), fmaxf(n02, n10)),
                      fmaxf(fmaxf(n11, n12), fmaxf(n20, n21)));
      m = fmaxf(m, n22);          // 0-pad == -inf pad for (> 0.1)
      alive_cur[P + lane] = (m > 0.1f) ? 1 : 0;
    }
  }

  // ---- Threefry (pure-register; fills conv-store / barrier latency) ----
  float keep[4];
  #pragma unroll
  for (int i = 0; i < 4; ++i) {
    const int cc = sub * 4 + i;
    const uint32_t j = (uint32_t)((b * CHN + cc) * HW + p);
    uint32_t o0, o1;
    tf2x32(k0, k1, 0u, j, o0, o1);
    const uint32_t bits = o0 ^ o1;
    keep[i] = ((bits >> 9) > 0x400000u) ? 1.f : 0.f;  // uniform>0.5 strict
  }

  __syncthreads();   // B0: y ready

  // ---- GEMM1: lane = px; acc[j] = h pair {sub*32+2j, sub*32+2j+1}[px].
  //      FULL unroll; w2 pairs wave-uniform (SGPR) -> v_pk_fma_f32. ----
  f32x2 acc[16];
  #pragma unroll
  for (int j = 0; j < 16; ++j) acc[j] = (f32x2){0.f, 0.f};

  const f32x2* w2b2 = (const f32x2*)(w2t + sub * 32);
  #pragma unroll
  for (int k = 0; k < 48; ++k) {
    const float yv = y_t[k * 66 + lane];
    const f32x2 yv2 = {yv, yv};
    const f32x2* w2r = w2b2 + k * 64;               // wave-uniform address
    #pragma unroll
    for (int j = 0; j < 16; ++j)
      acc[j] = __builtin_elementwise_fma(w2r[j], yv2, acc[j]);
  }

  // ---- GEMM2: relu in-register; FULL unroll (compile-time acc index);
  //      w3 pairs wave-uniform -> v_pk_fma_f32. hh ascending (same order). ----
  f32x2 o2[8];
  #pragma unroll
  for (int i = 0; i < 8; ++i) o2[i] = (f32x2){0.f, 0.f};

  const f32x2* w3b2 = (const f32x2*)(w3t + (size_t)sub * 32 * 16);
  #pragma unroll
  for (int hh = 0; hh < 32; ++hh) {
    const float av = (hh & 1) ? acc[hh >> 1].y : acc[hh >> 1].x;
    const float hv = fmaxf(av, 0.f);
    const f32x2 hv2 = {hv, hv};
    const f32x2* w3r = w3b2 + hh * 8;               // wave-uniform
    #pragma unroll
    for (int n = 0; n < 8; ++n)
      o2[n] = __builtin_elementwise_fma(w3r[n], hv2, o2[n]);
  }

  __syncthreads();   // B2: all y reads done; region becomes part[][][]

  #pragma unroll
  for (int cc = 0; cc < CHN; ++cc)
    part[cc][sub][lane] = (cc & 1) ? o2[cc >> 1].y : o2[cc >> 1].x;
  __syncthreads();   // B3

  // ---- Writeback: 4 (px,channel) per thread, coalesced; base value from
  //      the conv's (masked) center registers — no xin re-read. ----
  #pragma unroll
  for (int i = 0; i < 4; ++i) {
    const int cc = sub * 4 + i;
    const float s = (part[cc][0][lane] + part[cc][1][lane]) +
                    (part[cc][2][lane] + part[cc][3][lane]);
    const uint32_t j = (uint32_t)((b * CHN + cc) * HW + p);
    xnew[j] = n11m[i] + keep[i] * s;
  }
}

// Final mask pass (only for frames[23]): thread per (pixel, channel-quad).
__global__ __launch_bounds__(256) void nca_mask(
    const float* __restrict__ xnew, const uint8_t* __restrict__ alive_pre,
    float* __restrict__ xout)
{
  const int lane = threadIdx.x & 63;
  const int quad = threadIdx.x >> 6;            // 0..3
  const int bid  = blockIdx.x;
  const int vbid = (bid & 7) * 144 + (bid >> 3);   // same XCD swizzle
  const int pix  = vbid * 64 + lane;            // [0, NPIX)
  const int b = pix / HW;
  const int p = pix - b * HW;
  const int r = p / WW;
  const int c = p - r * WW;
  const bool rn = r > 0, rs = r < HH - 1, cw = c > 0, ce = c < WW - 1;

  const float* x3 = xnew + ((size_t)b * CHN + 3) * HW + p;
  float m = x3[0];
  if (rn) {
    m = fmaxf(m, x3[-WW]);
    if (cw) m = fmaxf(m, x3[-WW - 1]);
    if (ce) m = fmaxf(m, x3[-WW + 1]);
  }
  if (cw) m = fmaxf(m, x3[-1]);
  if (ce) m = fmaxf(m, x3[1]);
  if (rs) {
    m = fmaxf(m, x3[WW]);
    if (cw) m = fmaxf(m, x3[WW - 1]);
    if (ce) m = fmaxf(m, x3[WW + 1]);
  }
  const float f = ((m > 0.1f) && alive_pre[pix]) ? 1.f : 0.f;

  const size_t base = ((size_t)b * CHN + quad * 4) * HW + p;
  #pragma unroll
  for (int i = 0; i < 4; ++i)
    xout[base + (size_t)i * HW] = xnew[base + (size_t)i * HW] * f;
}

extern "C" void kernel_launch(void* const* d_in, const int* in_sizes, int n_in,
                              void* d_out, int out_size, void* d_ws, size_t ws_size,
                              hipStream_t stream) {
  const float* x0 = (const float*)d_in[0];
  // d_in[1] = num_steps (24, fixed), d_in[2] = dw_kernel (fixed, hardcoded)
  const float* w2 = (const float*)d_in[3];  // (128,48)
  const float* w3 = (const float*)d_in[4];  // (16,128)
  float* out = (float*)d_out;               // (24,8,16,96,96)

  // ws layout: xlast (xnew_23) | aliveA | aliveB | w3t | w2t  (~4.9 MB)
  char* ws = (char*)d_ws;
  float*   xlast  = (float*)ws;                                  // NELEM f32
  uint8_t* aliveA = (uint8_t*)(ws + (size_t)NELEM * 4);          // NPIX B
  uint8_t* aliveB = aliveA + NPIX;                               // NPIX B
  float*   w3t    = (float*)(ws + (size_t)NELEM * 4 + 2 * (size_t)NPIX);
  float*   w2t    = w3t + 2048;                                  // 6144 f32

  // Step keys: partitionable split => key_t = tf((0,42),(0,t)) full pair.
  uint32_t keys[T_STEPS][2];
  for (int t = 0; t < T_STEPS; ++t) {
    uint32_t a, b;
    tf2x32(0u, 42u, 0u, (uint32_t)t, a, b);
    keys[t][0] = a; keys[t][1] = b;
  }

  wt_transpose<<<32, 256, 0, stream>>>(w2, w3, w2t, w3t);

  // Buffer schedule: raw xnew_t parked in out[t+1] (free until frames[t+1]
  // lands there two dispatches later); xnew_23 goes to ws.
  //   F_0:  x0      -> out[1]
  //   F_t:  out[t]  -> frames[t-1]=out[t-1], xnew_t -> out[t+1] (t=1..22)
  //   F_23: out[23] -> frames[22]=out[22],  xnew_23 -> ws
  //   final mask: ws -> frames[23]=out[23]
  nca_step<false><<<NBLK, 256, 0, stream>>>(
      x0, nullptr, nullptr, out + (size_t)1 * NELEM, aliveA, w2t, w3t,
      keys[0][0], keys[0][1]);

  for (int t = 1; t < T_STEPS; ++t) {
    const float* xin  = out + (size_t)t * NELEM;          // raw xnew_{t-1}
    float* frames_prv = out + (size_t)(t - 1) * NELEM;
    float* xdst = (t < T_STEPS - 1) ? out + (size_t)(t + 1) * NELEM : xlast;
    const uint8_t* aprev = (t & 1) ? aliveA : aliveB;
    uint8_t*       acur  = (t & 1) ? aliveB : aliveA;
    nca_step<true><<<NBLK, 256, 0, stream>>>(
        xin, frames_prv, aprev, xdst, acur, w2t, w3t,
        keys[t][0], keys[t][1]);
  }

  nca_mask<<<NBLK, 256, 0, stream>>>(
      xlast, (T_STEPS & 1) ? aliveA : aliveB,
      out + (size_t)(T_STEPS - 1) * NELEM);
}